// Round 4
// baseline (857.346 us; speedup 1.0000x reference)
//
#include <hip/hip_runtime.h>

#define SENT 0xFFFFFFFFu

// ---------------- tables ----------------
__constant__ int c_tri[16][6] = {
 {-1,-1,-1,-1,-1,-1},{1,0,2,-1,-1,-1},{4,0,3,-1,-1,-1},{1,4,2,1,3,4},
 {3,1,5,-1,-1,-1},{2,3,0,2,5,3},{1,4,0,1,5,4},{4,2,5,-1,-1,-1},
 {4,5,2,-1,-1,-1},{4,1,0,4,5,1},{3,2,0,3,5,2},{1,3,5,-1,-1,-1},
 {4,1,2,4,3,1},{3,0,4,-1,-1,-1},{2,0,1,-1,-1,-1},{-1,-1,-1,-1,-1,-1}};
__constant__ int c_ntri[16] = {0,1,1,2,1,2,2,1,1,2,2,1,2,1,1,0};
__constant__ int c_ea[6] = {0,0,0,1,1,2};
__constant__ int c_eb[6] = {1,2,3,2,3,3};

// ---------------- utility ----------------
__global__ void k_zero_u32(unsigned* p, int n) {
    int i = blockIdx.x * blockDim.x + threadIdx.x;
    int st = gridDim.x * blockDim.x;
    for (; i < n; i += st) p[i] = 0u;
}

// zero only the padded tail rows (r >= V) of verts/vvalid
__global__ void k_zero_pad(const unsigned* __restrict__ total,
                           float* __restrict__ verts, float* __restrict__ vvalid, int nv) {
    int r = blockIdx.x * blockDim.x + threadIdx.x;
    if (r >= nv) return;
    unsigned V = *total;
    if ((unsigned)r < V) return;
    size_t b = (size_t)r * 3;
    verts[b + 0] = 0.f;
    verts[b + 1] = 0.f;
    verts[b + 2] = 0.f;
    vvalid[r] = 0.f;
}

// ---------------- scan (exclusive, n -> out[n+1]) ----------------
#define SBS 256
#define SIT 4

__global__ void k_scan1(const unsigned* in, unsigned* out, unsigned* bsum, int n) {
    __shared__ unsigned sm[SBS];
    int t = threadIdx.x, blk = blockIdx.x;
    int base = blk * SBS * SIT + t * SIT;
    unsigned v[SIT];
    unsigned tot = 0;
#pragma unroll
    for (int k = 0; k < SIT; k++) {
        v[k] = (base + k < n) ? in[base + k] : 0u;
        tot += v[k];
    }
    sm[t] = tot;
    __syncthreads();
    for (int off = 1; off < SBS; off <<= 1) {
        unsigned x = (t >= off) ? sm[t - off] : 0u;
        __syncthreads();
        sm[t] += x;
        __syncthreads();
    }
    unsigned run = (t == 0) ? 0u : sm[t - 1];
#pragma unroll
    for (int k = 0; k < SIT; k++) {
        if (base + k < n) out[base + k] = run;
        run += v[k];
    }
    if (t == SBS - 1) bsum[blk] = sm[SBS - 1];
}

__global__ void k_scan2(unsigned* bsum, unsigned* out, int nb, int n) {
    if (threadIdx.x == 0 && blockIdx.x == 0) {
        unsigned run = 0;
        for (int i = 0; i < nb; i++) {
            unsigned t = bsum[i];
            bsum[i] = run;
            run += t;
        }
        out[n] = run;  // grand total
    }
}

// adds block offsets; optionally duplicates result into dup[]
__global__ void k_scan3(unsigned* out, unsigned* dup, const unsigned* bsum, int n) {
    int t = threadIdx.x, blk = blockIdx.x;
    int base = blk * SBS * SIT + t * SIT;
    unsigned add = bsum[blk];
#pragma unroll
    for (int k = 0; k < SIT; k++) {
        if (base + k < n) {
            unsigned r = out[base + k] + add;
            out[base + k] = r;
            if (dup) dup[base + k] = r;
        }
    }
}

// ---------------- pipeline ----------------
// count crossing edges per min-vertex bucket; cache 4-bit occ code per tet
__global__ void k_count(const int* __restrict__ tet, const float* __restrict__ sdf,
                        unsigned* __restrict__ h, unsigned char* __restrict__ tcode, int F) {
    int f = blockIdx.x * blockDim.x + threadIdx.x;
    if (f >= F) return;
    int4 tv = ((const int4*)tet)[f];
    int v[4] = {tv.x, tv.y, tv.z, tv.w};
    int code = 0;
#pragma unroll
    for (int i = 0; i < 4; i++) code |= (sdf[v[i]] > 0.f) ? (1 << i) : 0;
    tcode[f] = (unsigned char)code;
    if (code == 0 || code == 15) return;
#pragma unroll
    for (int j = 0; j < 6; j++) {
        int i0 = c_ea[j], i1 = c_eb[j];
        if (((code >> i0) & 1) != ((code >> i1) & 1)) {
            int a = min(v[i0], v[i1]);
            atomicAdd(&h[a], 1u);
        }
    }
}

// scatter b values into bucket pools
__global__ void k_scatter(const int* __restrict__ tet, const unsigned char* __restrict__ tcode,
                          unsigned* __restrict__ cursor, unsigned* __restrict__ pool_b, int F) {
    int f = blockIdx.x * blockDim.x + threadIdx.x;
    if (f >= F) return;
    int code = tcode[f];
    if (code == 0 || code == 15) return;
    int4 tv = ((const int4*)tet)[f];
    int v[4] = {tv.x, tv.y, tv.z, tv.w};
#pragma unroll
    for (int j = 0; j < 6; j++) {
        int i0 = c_ea[j], i1 = c_eb[j];
        if (((code >> i0) & 1) != ((code >> i1) & 1)) {
            int a = min(v[i0], v[i1]);
            int b = max(v[i0], v[i1]);
            unsigned pos = atomicAdd(&cursor[a], 1u);
            pool_b[pos] = (unsigned)b;
        }
    }
}

// ---- bucket sort helpers (all writes coalesced, sentinel-padded tails) ----

__device__ __forceinline__ void sort_full(unsigned s, int m, int bucket, int lane,
                                          unsigned* __restrict__ pool_b,
                                          unsigned* __restrict__ cnt) {
    unsigned v = (lane < m) ? pool_b[s + lane] : SENT;
#pragma unroll
    for (int k = 2; k <= 64; k <<= 1) {
#pragma unroll
        for (int j = k >> 1; j >= 1; j >>= 1) {
            unsigned p = __shfl_xor(v, j, 64);
            bool takeMin = (((lane & k) == 0) == ((lane & j) == 0));
            unsigned mn = min(v, p), mx = max(v, p);
            v = takeMin ? mn : mx;
        }
    }
    unsigned pv = __shfl_up(v, 1, 64);
    bool valid = lane < m;
    bool uniq = valid && (lane == 0 || v != pv);
    unsigned long long um = __ballot(uniq);
    int d = __popcll(um);
    if (valid && lane >= d) pool_b[s + lane] = SENT;       // sentinel tail [d,m)
    if (uniq) {
        int pos = __popcll(um & ((1ull << lane) - 1ull));
        pool_b[s + pos] = v;                                // compact [0,d)
    }
    if (lane == 0) cnt[bucket] = (unsigned)d;
}

// two buckets (each m <= 32) in the two 32-lane halves
__device__ __forceinline__ void sort_pair(unsigned s_a, int m_a, int ba,
                                          unsigned s_b, int m_b, int bb, int N, int lane,
                                          unsigned* __restrict__ pool_b,
                                          unsigned* __restrict__ cnt) {
    int half = lane >> 5, hl = lane & 31;
    unsigned s = half ? s_b : s_a;
    int m = half ? m_b : m_a;
    unsigned v = (hl < m) ? pool_b[s + hl] : SENT;
#pragma unroll
    for (int k = 2; k <= 32; k <<= 1) {
#pragma unroll
        for (int j = k >> 1; j >= 1; j >>= 1) {
            unsigned p = __shfl_xor(v, j, 64);  // j<=16: stays within half
            bool takeMin = (((hl & k) == 0) == ((hl & j) == 0));
            unsigned mn = min(v, p), mx = max(v, p);
            v = takeMin ? mn : mx;
        }
    }
    unsigned pv = __shfl_up(v, 1, 64);  // hl==0 cross-half garbage excluded below
    bool valid = hl < m;
    bool uniq = valid && (hl == 0 || v != pv);
    unsigned long long um_all = __ballot(uniq);
    unsigned um = (unsigned)(um_all >> (half ? 32 : 0));
    int d = __popc(um);
    if (valid && hl >= d) pool_b[s + hl] = SENT;
    if (uniq) {
        int pos = __popc(um & ((1u << hl) - 1u));
        pool_b[s + pos] = v;
    }
    if (hl == 0) {
        int bkt = half ? bb : ba;
        if (bkt < N) cnt[bkt] = (unsigned)d;
    }
}

// rare fallback m > 64
__device__ __forceinline__ void serial_bucket(unsigned s, int m, int bucket, int lane,
                                              unsigned* __restrict__ pool_b,
                                              unsigned* __restrict__ cnt) {
    if (lane != 0) return;
    for (int i = 1; i < m; i++) {
        unsigned kv = pool_b[s + i];
        int j = i - 1;
        while (j >= 0 && pool_b[s + j] > kv) {
            pool_b[s + j + 1] = pool_b[s + j];
            j--;
        }
        pool_b[s + j + 1] = kv;
    }
    int d = 0;
    unsigned prev = SENT;
    for (int i = 0; i < m; i++) {
        unsigned bv = pool_b[s + i];
        if (bv != prev) { pool_b[s + d] = bv; d++; prev = bv; }
    }
    for (int i = d; i < m; i++) pool_b[s + i] = SENT;
    cnt[bucket] = (unsigned)d;
}

// wave handles 4 consecutive buckets
__global__ void k_bucket_sort(const unsigned* __restrict__ scat_base,
                              unsigned* __restrict__ pool_b,
                              unsigned* __restrict__ cnt, int N) {
    int wid = (int)((blockIdx.x * blockDim.x + threadIdx.x) >> 6);
    int lane = threadIdx.x & 63;
    int b0 = wid * 4;
    if (b0 >= N) return;
    unsigned sb[5];
#pragma unroll
    for (int i = 0; i < 5; i++) sb[i] = scat_base[min(b0 + i, N)];
#pragma unroll
    for (int p = 0; p < 2; p++) {
        int ba = b0 + 2 * p, bb = ba + 1;
        if (ba >= N) break;
        unsigned s_a = sb[2 * p];
        int m_a = (int)(sb[2 * p + 1] - sb[2 * p]);
        unsigned s_b = sb[2 * p + 1];
        int m_b = (int)(sb[2 * p + 2] - sb[2 * p + 1]);
        if (m_a <= 32 && m_b <= 32) {
            sort_pair(s_a, m_a, ba, s_b, m_b, bb, N, lane, pool_b, cnt);
        } else {
            if (m_a <= 64) sort_full(s_a, m_a, ba, lane, pool_b, cnt);
            else           serial_bucket(s_a, m_a, ba, lane, pool_b, cnt);
            if (bb < N) {
                if (m_b <= 64) sort_full(s_b, m_b, bb, lane, pool_b, cnt);
                else           serial_bucket(s_b, m_b, bb, lane, pool_b, cnt);
            }
        }
    }
}

// wave-per-bucket vert writer (lane-per-element; dense coalesced output)
__global__ void k_verts(const float* __restrict__ pos, const float* __restrict__ sdf,
                        const unsigned* __restrict__ scat_base, const unsigned* __restrict__ cnt,
                        const unsigned* __restrict__ rank_base, const unsigned* __restrict__ pool_b,
                        float* __restrict__ verts, float* __restrict__ vvalid, int N) {
    int a = (int)((blockIdx.x * blockDim.x + threadIdx.x) >> 6);
    int lane = threadIdx.x & 63;
    if (a >= N) return;
    int d = (int)cnt[a];
    if (d == 0) return;
    unsigned s = scat_base[a];
    unsigned rb = rank_base[a];
    float sa = sdf[a];
    float pax = pos[(size_t)a * 3 + 0];
    float pay = pos[(size_t)a * 3 + 1];
    float paz = pos[(size_t)a * 3 + 2];
    for (int i = lane; i < d; i += 64) {
        unsigned b = pool_b[s + i];
        float sbv = sdf[b];
        float denom = sa - sbv;
        float w0 = (-sbv) / denom;
        float w1 = sa / denom;
        size_t r = (size_t)(rb + i);
        verts[r * 3 + 0] = pax * w0 + pos[(size_t)b * 3 + 0] * w1;
        verts[r * 3 + 1] = pay * w0 + pos[(size_t)b * 3 + 1] * w1;
        verts[r * 3 + 2] = paz * w0 + pos[(size_t)b * 3 + 2] * w1;
        vvalid[r] = 1.0f;
    }
}

// lower_bound over the full bucket span (sorted thanks to sentinel-padded tail)
__device__ __forceinline__ float edge_rank(int A, int B,
                                           const unsigned* __restrict__ scat_base,
                                           const unsigned* __restrict__ rank_base,
                                           const unsigned* __restrict__ pool_b) {
    unsigned s = scat_base[A];
    int m = (int)(scat_base[A + 1] - s);
    int lo = 0, hi = m;
    unsigned ub = (unsigned)B;
    while (lo < hi) {
        int mid = (lo + hi) >> 1;
        if (pool_b[s + mid] < ub) lo = mid + 1;
        else hi = mid;
    }
    return (float)(rank_base[A] + (unsigned)lo);
}

// faces + face_valid (writes every slot -> deterministic)
__global__ void k_faces(const int* __restrict__ tet, const unsigned char* __restrict__ tcode,
                        const unsigned* __restrict__ scat_base,
                        const unsigned* __restrict__ rank_base,
                        const unsigned* __restrict__ pool_b,
                        float* __restrict__ faces, float* __restrict__ fvalid, int F) {
    int f = blockIdx.x * blockDim.x + threadIdx.x;
    if (f >= F) return;
    int code = tcode[f];
    int nt = c_ntri[code];
    size_t r0 = (size_t)f * 3;
    size_t r1 = ((size_t)F + f) * 3;
    if (nt == 0) {
        faces[r0 + 0] = -1.f; faces[r0 + 1] = -1.f; faces[r0 + 2] = -1.f;
        faces[r1 + 0] = -1.f; faces[r1 + 1] = -1.f; faces[r1 + 2] = -1.f;
        fvalid[f] = 0.f;
        fvalid[F + f] = 0.f;
        return;
    }
    int4 tv = ((const int4*)tet)[f];
    int v[4] = {tv.x, tv.y, tv.z, tv.w};
    float f0[3], f1[3] = {-1.f, -1.f, -1.f};
#pragma unroll
    for (int k = 0; k < 3; k++) {
        int e = c_tri[code][k];
        int va = v[c_ea[e]], vb = v[c_eb[e]];
        int A = min(va, vb), B = max(va, vb);
        f0[k] = edge_rank(A, B, scat_base, rank_base, pool_b);
    }
    if (nt == 2) {
#pragma unroll
        for (int k = 0; k < 3; k++) {
            int e = c_tri[code][3 + k];
            int va = v[c_ea[e]], vb = v[c_eb[e]];
            int A = min(va, vb), B = max(va, vb);
            f1[k] = edge_rank(A, B, scat_base, rank_base, pool_b);
        }
    }
    faces[r0 + 0] = f0[0]; faces[r0 + 1] = f0[1]; faces[r0 + 2] = f0[2];
    faces[r1 + 0] = f1[0]; faces[r1 + 1] = f1[1]; faces[r1 + 2] = f1[2];
    fvalid[f] = 1.f;
    fvalid[F + f] = (nt == 2) ? 1.f : 0.f;
}

// ---------------- host launch ----------------
static void run_scan(const unsigned* in, unsigned* out, unsigned* dup, unsigned* bsum,
                     int n, hipStream_t stream) {
    int nb = (n + SBS * SIT - 1) / (SBS * SIT);
    k_scan1<<<nb, SBS, 0, stream>>>(in, out, bsum, n);
    k_scan2<<<1, 64, 0, stream>>>(bsum, out, nb, n);
    k_scan3<<<nb, SBS, 0, stream>>>(out, dup, bsum, n);
}

extern "C" void kernel_launch(void* const* d_in, const int* in_sizes, int n_in,
                              void* d_out, int out_size, void* d_ws, size_t ws_size,
                              hipStream_t stream) {
    const float* pos = (const float*)d_in[0];
    const float* sdf = (const float*)d_in[1];
    const int* tet = (const int*)d_in[2];
    const int N = in_sizes[1];
    const int F = in_sizes[2] / 4;
    const int E = F * 6;

    float* out = (float*)d_out;
    size_t nverts = (size_t)6 * F;
    size_t nfaces = (size_t)2 * F;
    float* o_verts = out;                    // [6F,3]
    float* o_faces = out + nverts * 3;       // [2F,3]
    float* o_vvalid = o_faces + nfaces * 3;  // [6F]
    float* o_fvalid = o_vvalid + nverts;     // [2F]

    // workspace layout (u32): ~ (5N + E)*4 + F bytes ≈ 29 MB
    unsigned* w = (unsigned*)d_ws;
    unsigned* h = w;                        // N
    unsigned* scat_base = h + N;            // N+1
    unsigned* cursor = scat_base + N + 1;   // N
    unsigned* cnt = cursor + N;             // N
    unsigned* rank_base = cnt + N;          // N+1
    unsigned* bsum = rank_base + N + 1;     // 4096
    unsigned* pool_b = bsum + 4096;         // E
    unsigned char* tcode = (unsigned char*)(pool_b + E);  // F

    const int BS = 256;
    int gF = (F + BS - 1) / BS;
    int gN = (N + BS - 1) / BS;
    int gW = (N + 3) / 4;        // wave-per-bucket blocks
    int gW4 = (N + 15) / 16;     // wave-per-4-buckets blocks
    int gV = (int)((nverts + BS - 1) / BS);

    // 1. zero histogram
    k_zero_u32<<<gN, BS, 0, stream>>>(h, N);

    // 2. count crossing edges per bucket + cache occ codes
    k_count<<<gF, BS, 0, stream>>>(tet, sdf, h, tcode, F);

    // 3. scan -> scatter bases (+ cursor copy fused)
    run_scan(h, scat_base, cursor, bsum, N, stream);

    // 4. scatter b values
    k_scatter<<<gF, BS, 0, stream>>>(tet, tcode, cursor, pool_b, F);

    // 5. size-adaptive bucket sort + dedupe (sentinel-padded tails)
    k_bucket_sort<<<gW4, BS, 0, stream>>>(scat_base, pool_b, cnt, N);

    // 6. scan distinct counts -> global vert ranks (total at rank_base[N])
    run_scan(cnt, rank_base, nullptr, bsum, N, stream);

    // 7. zero only padded vert rows
    k_zero_pad<<<gV, BS, 0, stream>>>(rank_base + N, o_verts, o_vvalid, (int)nverts);

    // 8. verts (wave per bucket)
    k_verts<<<gW, BS, 0, stream>>>(pos, sdf, scat_base, cnt, rank_base, pool_b,
                                   o_verts, o_vvalid, N);

    // 9. faces via per-edge lower_bound (cacheable gathers)
    k_faces<<<gF, BS, 0, stream>>>(tet, tcode, scat_base, rank_base, pool_b,
                                   o_faces, o_fvalid, F);
}

// Round 5
// 677.170 us; speedup vs baseline: 1.2661x; 1.2661x over previous
//
#include <hip/hip_runtime.h>

#define SENT 0xFFFFFFFFu
#define BIN_SHIFT 10
#define BIN_W (1 << BIN_SHIFT)
#define MAXBIN 2048  // supports N up to 2M

// ---------------- tables ----------------
__constant__ int c_tri[16][6] = {
 {-1,-1,-1,-1,-1,-1},{1,0,2,-1,-1,-1},{4,0,3,-1,-1,-1},{1,4,2,1,3,4},
 {3,1,5,-1,-1,-1},{2,3,0,2,5,3},{1,4,0,1,5,4},{4,2,5,-1,-1,-1},
 {4,5,2,-1,-1,-1},{4,1,0,4,5,1},{3,2,0,3,5,2},{1,3,5,-1,-1,-1},
 {4,1,2,4,3,1},{3,0,4,-1,-1,-1},{2,0,1,-1,-1,-1},{-1,-1,-1,-1,-1,-1}};
__constant__ int c_ntri[16] = {0,1,1,2,1,2,2,1,1,2,2,1,2,1,1,0};
__constant__ int c_ea[6] = {0,0,0,1,1,2};
__constant__ int c_eb[6] = {1,2,3,2,3,3};

// ---------------- utility ----------------
__global__ void k_zero_u32(unsigned* p, int n) {
    int i = blockIdx.x * blockDim.x + threadIdx.x;
    int st = gridDim.x * blockDim.x;
    for (; i < n; i += st) p[i] = 0u;
}

// zero only the padded tail rows (r >= V) of verts/vvalid
__global__ void k_zero_pad(const unsigned* __restrict__ total,
                           float* __restrict__ verts, float* __restrict__ vvalid, int nv) {
    int r = blockIdx.x * blockDim.x + threadIdx.x;
    if (r >= nv) return;
    unsigned V = *total;
    if ((unsigned)r < V) return;
    size_t b = (size_t)r * 3;
    verts[b + 0] = 0.f;
    verts[b + 1] = 0.f;
    verts[b + 2] = 0.f;
    vvalid[r] = 0.f;
}

// ---------------- scan (exclusive, n -> out[n+1]) ----------------
#define SBS 256
#define SIT 4

__global__ void k_scan1(const unsigned* in, unsigned* out, unsigned* bsum, int n) {
    __shared__ unsigned sm[SBS];
    int t = threadIdx.x, blk = blockIdx.x;
    int base = blk * SBS * SIT + t * SIT;
    unsigned v[SIT];
    unsigned tot = 0;
#pragma unroll
    for (int k = 0; k < SIT; k++) {
        v[k] = (base + k < n) ? in[base + k] : 0u;
        tot += v[k];
    }
    sm[t] = tot;
    __syncthreads();
    for (int off = 1; off < SBS; off <<= 1) {
        unsigned x = (t >= off) ? sm[t - off] : 0u;
        __syncthreads();
        sm[t] += x;
        __syncthreads();
    }
    unsigned run = (t == 0) ? 0u : sm[t - 1];
#pragma unroll
    for (int k = 0; k < SIT; k++) {
        if (base + k < n) out[base + k] = run;
        run += v[k];
    }
    if (t == SBS - 1) bsum[blk] = sm[SBS - 1];
}

__global__ void k_scan2(unsigned* bsum, unsigned* out, int nb, int n) {
    if (threadIdx.x == 0 && blockIdx.x == 0) {
        unsigned run = 0;
        for (int i = 0; i < nb; i++) {
            unsigned t = bsum[i];
            bsum[i] = run;
            run += t;
        }
        out[n] = run;  // grand total
    }
}

__global__ void k_scan3(unsigned* out, const unsigned* bsum, int n) {
    int t = threadIdx.x, blk = blockIdx.x;
    int base = blk * SBS * SIT + t * SIT;
    unsigned add = bsum[blk];
#pragma unroll
    for (int k = 0; k < SIT; k++) {
        if (base + k < n) out[base + k] += add;
    }
}

// ---------------- pipeline ----------------
// count crossing edges per min-vertex bucket; cache 4-bit occ code per tet
__global__ void k_count(const int* __restrict__ tet, const float* __restrict__ sdf,
                        unsigned* __restrict__ h, unsigned char* __restrict__ tcode, int F) {
    int f = blockIdx.x * blockDim.x + threadIdx.x;
    if (f >= F) return;
    int4 tv = ((const int4*)tet)[f];
    int v[4] = {tv.x, tv.y, tv.z, tv.w};
    int code = 0;
#pragma unroll
    for (int i = 0; i < 4; i++) code |= (sdf[v[i]] > 0.f) ? (1 << i) : 0;
    tcode[f] = (unsigned char)code;
    if (code == 0 || code == 15) return;
#pragma unroll
    for (int j = 0; j < 6; j++) {
        int i0 = c_ea[j], i1 = c_eb[j];
        if (((code >> i0) & 1) != ((code >> i1) & 1)) {
            int a = min(v[i0], v[i1]);
            atomicAdd(&h[a], 1u);
        }
    }
}

// coarse cursors = pool region starts per bin (pool is ordered by a)
__global__ void k_init_coarse(const unsigned* __restrict__ scat_base,
                              unsigned* __restrict__ coarse, int nbin, int N) {
    int i = blockIdx.x * blockDim.x + threadIdx.x;
    if (i < nbin) coarse[i] = scat_base[min(i << BIN_SHIFT, N)];
}

// level 1: LDS-binned scatter of (a,b) into coarse-bin-contiguous temp chunks
__global__ void k_binscatter(const int* __restrict__ tet, const unsigned char* __restrict__ tcode,
                             unsigned* __restrict__ coarse, uint2* __restrict__ temp_ab,
                             int F, int nbin) {
    __shared__ unsigned s_cnt[MAXBIN];
    __shared__ unsigned s_base[MAXBIN];
    int tid = threadIdx.x;
    for (int i = tid; i < nbin; i += blockDim.x) s_cnt[i] = 0;
    __syncthreads();

    int base = blockIdx.x * (int)blockDim.x * 4;
    int4 tv[4];
    int code[4];
#pragma unroll
    for (int k = 0; k < 4; k++) {
        int f = base + k * (int)blockDim.x + tid;
        code[k] = 0;
        if (f < F) {
            int c = tcode[f];
            if (c != 0 && c != 15) {
                code[k] = c;
                tv[k] = ((const int4*)tet)[f];
            }
        }
    }
    // count into LDS bins
#pragma unroll
    for (int k = 0; k < 4; k++) {
        if (!code[k]) continue;
        int v[4] = {tv[k].x, tv[k].y, tv[k].z, tv[k].w};
#pragma unroll
        for (int j = 0; j < 6; j++) {
            int i0 = c_ea[j], i1 = c_eb[j];
            if (((code[k] >> i0) & 1) != ((code[k] >> i1) & 1)) {
                int a = min(v[i0], v[i1]);
                atomicAdd(&s_cnt[a >> BIN_SHIFT], 1u);
            }
        }
    }
    __syncthreads();
    // reserve per-bin chunks globally; reset LDS counters for write pass
    for (int i = tid; i < nbin; i += blockDim.x) {
        unsigned c = s_cnt[i];
        s_base[i] = c ? atomicAdd(&coarse[i], c) : 0u;
        s_cnt[i] = 0;
    }
    __syncthreads();
    // write (a,b) into this block's chunk of each bin
#pragma unroll
    for (int k = 0; k < 4; k++) {
        if (!code[k]) continue;
        int v[4] = {tv[k].x, tv[k].y, tv[k].z, tv[k].w};
#pragma unroll
        for (int j = 0; j < 6; j++) {
            int i0 = c_ea[j], i1 = c_eb[j];
            if (((code[k] >> i0) & 1) != ((code[k] >> i1) & 1)) {
                int a = min(v[i0], v[i1]);
                int b = max(v[i0], v[i1]);
                int bin = a >> BIN_SHIFT;
                unsigned pos = s_base[bin] + atomicAdd(&s_cnt[bin], 1u);
                temp_ab[pos] = make_uint2((unsigned)a, (unsigned)b);
            }
        }
    }
}

// level 2: one block per bin; LDS per-a cursors; writes stay in the bin's
// pool window (~100 KB) -> L2-resident, ~1x writeback
__global__ void k_fine(const unsigned* __restrict__ scat_base,
                       const uint2* __restrict__ temp_ab,
                       unsigned* __restrict__ pool_b, int N) {
    __shared__ unsigned s_cur[BIN_W];
    int bin = blockIdx.x;
    int a0 = bin << BIN_SHIFT;
    int a1 = min(a0 + BIN_W, N);
    int w = a1 - a0;
    for (int i = threadIdx.x; i < w; i += blockDim.x) s_cur[i] = scat_base[a0 + i];
    __syncthreads();
    unsigned start = scat_base[a0];
    unsigned end = scat_base[a1];
    for (unsigned idx = start + threadIdx.x; idx < end; idx += blockDim.x) {
        uint2 ab = temp_ab[idx];
        unsigned pos = atomicAdd(&s_cur[ab.x - (unsigned)a0], 1u);
        pool_b[pos] = ab.y;
    }
}

// ---- bucket sort helpers (all writes coalesced, sentinel-padded tails) ----

__device__ __forceinline__ void sort_full(unsigned s, int m, int bucket, int lane,
                                          unsigned* __restrict__ pool_b,
                                          unsigned* __restrict__ cnt) {
    unsigned v = (lane < m) ? pool_b[s + lane] : SENT;
#pragma unroll
    for (int k = 2; k <= 64; k <<= 1) {
#pragma unroll
        for (int j = k >> 1; j >= 1; j >>= 1) {
            unsigned p = __shfl_xor(v, j, 64);
            bool takeMin = (((lane & k) == 0) == ((lane & j) == 0));
            unsigned mn = min(v, p), mx = max(v, p);
            v = takeMin ? mn : mx;
        }
    }
    unsigned pv = __shfl_up(v, 1, 64);
    bool valid = lane < m;
    bool uniq = valid && (lane == 0 || v != pv);
    unsigned long long um = __ballot(uniq);
    int d = __popcll(um);
    if (valid && lane >= d) pool_b[s + lane] = SENT;       // sentinel tail [d,m)
    if (uniq) {
        int pos = __popcll(um & ((1ull << lane) - 1ull));
        pool_b[s + pos] = v;                                // compact [0,d)
    }
    if (lane == 0) cnt[bucket] = (unsigned)d;
}

__device__ __forceinline__ void sort_pair(unsigned s_a, int m_a, int ba,
                                          unsigned s_b, int m_b, int bb, int N, int lane,
                                          unsigned* __restrict__ pool_b,
                                          unsigned* __restrict__ cnt) {
    int half = lane >> 5, hl = lane & 31;
    unsigned s = half ? s_b : s_a;
    int m = half ? m_b : m_a;
    unsigned v = (hl < m) ? pool_b[s + hl] : SENT;
#pragma unroll
    for (int k = 2; k <= 32; k <<= 1) {
#pragma unroll
        for (int j = k >> 1; j >= 1; j >>= 1) {
            unsigned p = __shfl_xor(v, j, 64);  // j<=16: stays within half
            bool takeMin = (((hl & k) == 0) == ((hl & j) == 0));
            unsigned mn = min(v, p), mx = max(v, p);
            v = takeMin ? mn : mx;
        }
    }
    unsigned pv = __shfl_up(v, 1, 64);
    bool valid = hl < m;
    bool uniq = valid && (hl == 0 || v != pv);
    unsigned long long um_all = __ballot(uniq);
    unsigned um = (unsigned)(um_all >> (half ? 32 : 0));
    int d = __popc(um);
    if (valid && hl >= d) pool_b[s + hl] = SENT;
    if (uniq) {
        int pos = __popc(um & ((1u << hl) - 1u));
        pool_b[s + pos] = v;
    }
    if (hl == 0) {
        int bkt = half ? bb : ba;
        if (bkt < N) cnt[bkt] = (unsigned)d;
    }
}

__device__ __forceinline__ void serial_bucket(unsigned s, int m, int bucket, int lane,
                                              unsigned* __restrict__ pool_b,
                                              unsigned* __restrict__ cnt) {
    if (lane != 0) return;
    for (int i = 1; i < m; i++) {
        unsigned kv = pool_b[s + i];
        int j = i - 1;
        while (j >= 0 && pool_b[s + j] > kv) {
            pool_b[s + j + 1] = pool_b[s + j];
            j--;
        }
        pool_b[s + j + 1] = kv;
    }
    int d = 0;
    unsigned prev = SENT;
    for (int i = 0; i < m; i++) {
        unsigned bv = pool_b[s + i];
        if (bv != prev) { pool_b[s + d] = bv; d++; prev = bv; }
    }
    for (int i = d; i < m; i++) pool_b[s + i] = SENT;
    cnt[bucket] = (unsigned)d;
}

// wave handles 4 consecutive buckets
__global__ void k_bucket_sort(const unsigned* __restrict__ scat_base,
                              unsigned* __restrict__ pool_b,
                              unsigned* __restrict__ cnt, int N) {
    int wid = (int)((blockIdx.x * blockDim.x + threadIdx.x) >> 6);
    int lane = threadIdx.x & 63;
    int b0 = wid * 4;
    if (b0 >= N) return;
    unsigned sb[5];
#pragma unroll
    for (int i = 0; i < 5; i++) sb[i] = scat_base[min(b0 + i, N)];
#pragma unroll
    for (int p = 0; p < 2; p++) {
        int ba = b0 + 2 * p, bb = ba + 1;
        if (ba >= N) break;
        unsigned s_a = sb[2 * p];
        int m_a = (int)(sb[2 * p + 1] - sb[2 * p]);
        unsigned s_b = sb[2 * p + 1];
        int m_b = (int)(sb[2 * p + 2] - sb[2 * p + 1]);
        if (m_a <= 32 && m_b <= 32) {
            sort_pair(s_a, m_a, ba, s_b, m_b, bb, N, lane, pool_b, cnt);
        } else {
            if (m_a <= 64) sort_full(s_a, m_a, ba, lane, pool_b, cnt);
            else           serial_bucket(s_a, m_a, ba, lane, pool_b, cnt);
            if (bb < N) {
                if (m_b <= 64) sort_full(s_b, m_b, bb, lane, pool_b, cnt);
                else           serial_bucket(s_b, m_b, bb, lane, pool_b, cnt);
            }
        }
    }
}

// wave-per-bucket vert writer (lane-per-element; dense coalesced output)
__global__ void k_verts(const float* __restrict__ pos, const float* __restrict__ sdf,
                        const unsigned* __restrict__ scat_base, const unsigned* __restrict__ cnt,
                        const unsigned* __restrict__ rank_base, const unsigned* __restrict__ pool_b,
                        float* __restrict__ verts, float* __restrict__ vvalid, int N) {
    int a = (int)((blockIdx.x * blockDim.x + threadIdx.x) >> 6);
    int lane = threadIdx.x & 63;
    if (a >= N) return;
    int d = (int)cnt[a];
    if (d == 0) return;
    unsigned s = scat_base[a];
    unsigned rb = rank_base[a];
    float sa = sdf[a];
    float pax = pos[(size_t)a * 3 + 0];
    float pay = pos[(size_t)a * 3 + 1];
    float paz = pos[(size_t)a * 3 + 2];
    for (int i = lane; i < d; i += 64) {
        unsigned b = pool_b[s + i];
        float sbv = sdf[b];
        float denom = sa - sbv;
        float w0 = (-sbv) / denom;
        float w1 = sa / denom;
        size_t r = (size_t)(rb + i);
        verts[r * 3 + 0] = pax * w0 + pos[(size_t)b * 3 + 0] * w1;
        verts[r * 3 + 1] = pay * w0 + pos[(size_t)b * 3 + 1] * w1;
        verts[r * 3 + 2] = paz * w0 + pos[(size_t)b * 3 + 2] * w1;
        vvalid[r] = 1.0f;
    }
}

// lower_bound over the full bucket span (sorted thanks to sentinel-padded tail)
__device__ __forceinline__ float edge_rank(int A, int B,
                                           const unsigned* __restrict__ scat_base,
                                           const unsigned* __restrict__ rank_base,
                                           const unsigned* __restrict__ pool_b) {
    unsigned s = scat_base[A];
    int m = (int)(scat_base[A + 1] - s);
    int lo = 0, hi = m;
    unsigned ub = (unsigned)B;
    while (lo < hi) {
        int mid = (lo + hi) >> 1;
        if (pool_b[s + mid] < ub) lo = mid + 1;
        else hi = mid;
    }
    return (float)(rank_base[A] + (unsigned)lo);
}

// faces + face_valid (writes every slot -> deterministic)
__global__ void k_faces(const int* __restrict__ tet, const unsigned char* __restrict__ tcode,
                        const unsigned* __restrict__ scat_base,
                        const unsigned* __restrict__ rank_base,
                        const unsigned* __restrict__ pool_b,
                        float* __restrict__ faces, float* __restrict__ fvalid, int F) {
    int f = blockIdx.x * blockDim.x + threadIdx.x;
    if (f >= F) return;
    int code = tcode[f];
    int nt = c_ntri[code];
    size_t r0 = (size_t)f * 3;
    size_t r1 = ((size_t)F + f) * 3;
    if (nt == 0) {
        faces[r0 + 0] = -1.f; faces[r0 + 1] = -1.f; faces[r0 + 2] = -1.f;
        faces[r1 + 0] = -1.f; faces[r1 + 1] = -1.f; faces[r1 + 2] = -1.f;
        fvalid[f] = 0.f;
        fvalid[F + f] = 0.f;
        return;
    }
    int4 tv = ((const int4*)tet)[f];
    int v[4] = {tv.x, tv.y, tv.z, tv.w};
    float f0[3], f1[3] = {-1.f, -1.f, -1.f};
#pragma unroll
    for (int k = 0; k < 3; k++) {
        int e = c_tri[code][k];
        int va = v[c_ea[e]], vb = v[c_eb[e]];
        int A = min(va, vb), B = max(va, vb);
        f0[k] = edge_rank(A, B, scat_base, rank_base, pool_b);
    }
    if (nt == 2) {
#pragma unroll
        for (int k = 0; k < 3; k++) {
            int e = c_tri[code][3 + k];
            int va = v[c_ea[e]], vb = v[c_eb[e]];
            int A = min(va, vb), B = max(va, vb);
            f1[k] = edge_rank(A, B, scat_base, rank_base, pool_b);
        }
    }
    faces[r0 + 0] = f0[0]; faces[r0 + 1] = f0[1]; faces[r0 + 2] = f0[2];
    faces[r1 + 0] = f1[0]; faces[r1 + 1] = f1[1]; faces[r1 + 2] = f1[2];
    fvalid[f] = 1.f;
    fvalid[F + f] = (nt == 2) ? 1.f : 0.f;
}

// ---------------- host launch ----------------
static void run_scan(const unsigned* in, unsigned* out, unsigned* bsum,
                     int n, hipStream_t stream) {
    int nb = (n + SBS * SIT - 1) / (SBS * SIT);
    k_scan1<<<nb, SBS, 0, stream>>>(in, out, bsum, n);
    k_scan2<<<1, 64, 0, stream>>>(bsum, out, nb, n);
    k_scan3<<<nb, SBS, 0, stream>>>(out, bsum, n);
}

extern "C" void kernel_launch(void* const* d_in, const int* in_sizes, int n_in,
                              void* d_out, int out_size, void* d_ws, size_t ws_size,
                              hipStream_t stream) {
    const float* pos = (const float*)d_in[0];
    const float* sdf = (const float*)d_in[1];
    const int* tet = (const int*)d_in[2];
    const int N = in_sizes[1];
    const int F = in_sizes[2] / 4;
    const int E = F * 6;
    const int nbin = (N + BIN_W - 1) >> BIN_SHIFT;

    float* out = (float*)d_out;
    size_t nverts = (size_t)6 * F;
    size_t nfaces = (size_t)2 * F;
    float* o_verts = out;                    // [6F,3]
    float* o_faces = out + nverts * 3;       // [2F,3]
    float* o_vvalid = o_faces + nfaces * 3;  // [6F]
    float* o_fvalid = o_vvalid + nverts;     // [2F]

    // workspace (u32): 4N + ~6k + E + F/4 + 2E(uint2, 8B-aligned) ≈ 76 MB
    unsigned* w = (unsigned*)d_ws;
    unsigned* h = w;                        // N
    unsigned* scat_base = h + N;            // N+1
    unsigned* cnt = scat_base + N + 1;      // N
    unsigned* rank_base = cnt + N;          // N+1
    unsigned* bsum = rank_base + N + 1;     // 4096
    unsigned* coarse = bsum + 4096;         // MAXBIN
    unsigned* pool_b = coarse + MAXBIN;     // E
    unsigned char* tcode = (unsigned char*)(pool_b + E);          // F bytes
    size_t tb_off = ((size_t)(4 * N + 2 + 4096 + MAXBIN + E) + (F + 3) / 4 + 1) & ~(size_t)1;
    uint2* temp_ab = (uint2*)(w + tb_off);  // E uint2

    const int BS = 256;
    int gF = (F + BS - 1) / BS;
    int gN = (N + BS - 1) / BS;
    int gW = (N + 3) / 4;        // wave-per-bucket blocks
    int gW4 = (N + 15) / 16;     // wave-per-4-buckets blocks
    int gV = (int)((nverts + BS - 1) / BS);
    int gB = (F + BS * 4 - 1) / (BS * 4);

    // 1. zero histogram
    k_zero_u32<<<gN, BS, 0, stream>>>(h, N);

    // 2. count crossing edges per bucket + cache occ codes
    k_count<<<gF, BS, 0, stream>>>(tet, sdf, h, tcode, F);

    // 3. scan -> scatter bases
    run_scan(h, scat_base, bsum, N, stream);

    // 4. two-level scatter: coarse (coalesced chunks) then fine (L2-local)
    k_init_coarse<<<(nbin + 63) / 64, 64, 0, stream>>>(scat_base, coarse, nbin, N);
    k_binscatter<<<gB, BS, 0, stream>>>(tet, tcode, coarse, temp_ab, F, nbin);
    k_fine<<<nbin, BS, 0, stream>>>(scat_base, temp_ab, pool_b, N);

    // 5. size-adaptive bucket sort + dedupe (sentinel-padded tails)
    k_bucket_sort<<<gW4, BS, 0, stream>>>(scat_base, pool_b, cnt, N);

    // 6. scan distinct counts -> global vert ranks (total at rank_base[N])
    run_scan(cnt, rank_base, bsum, N, stream);

    // 7. zero only padded vert rows
    k_zero_pad<<<gV, BS, 0, stream>>>(rank_base + N, o_verts, o_vvalid, (int)nverts);

    // 8. verts (wave per bucket)
    k_verts<<<gW, BS, 0, stream>>>(pos, sdf, scat_base, cnt, rank_base, pool_b,
                                   o_verts, o_vvalid, N);

    // 9. faces via per-edge lower_bound (cacheable gathers)
    k_faces<<<gF, BS, 0, stream>>>(tet, tcode, scat_base, rank_base, pool_b,
                                   o_faces, o_fvalid, F);
}